// Round 17
// baseline (107.498 us; speedup 1.0000x reference)
//
#include <hip/hip_runtime.h>
#include <math.h>

#define BB 256
#define NN 1000
#define DD 128
#define HH 8
#define NEG -1e9f

#define SY_CNTA 0
#define SY_QK   1
#define SY_CNTC 2
#define SY_GQ   3
#define SY_CNTE 4

__device__ __forceinline__ bool get_mask(const void* m, int flag, size_t idx) {
    if (flag == 1) return ((const int*)m)[idx] != 0;
    if (flag == 2) return ((const float*)m)[idx] != 0.0f;
    return ((const unsigned char*)m)[idx] != 0;
}

__device__ __forceinline__ void sy_arrive(int* p) {
    __builtin_amdgcn_fence(__ATOMIC_RELEASE, "agent");
    __hip_atomic_fetch_add(p, 1, __ATOMIC_RELAXED, __HIP_MEMORY_SCOPE_AGENT);
}
__device__ __forceinline__ void sy_set(int* p) {
    __builtin_amdgcn_fence(__ATOMIC_RELEASE, "agent");
    __hip_atomic_store(p, 1, __ATOMIC_RELAXED, __HIP_MEMORY_SCOPE_AGENT);
}
__device__ __forceinline__ void sy_wait(int* p, int tgt) {
    while (__hip_atomic_load(p, __ATOMIC_RELAXED, __HIP_MEMORY_SCOPE_AGENT) < tgt)
        __builtin_amdgcn_s_sleep(8);
    __builtin_amdgcn_fence(__ATOMIC_ACQUIRE, "agent");
}

// ===========================================================================
// Spin-sync fused kernel, templated on chunks-per-b.
// CC=8: grid 2048, 8 blocks/CU (32 waves/CU), LDS ~13 KB, VGPR <= 64.
// CC=4: grid 1024, 4 blocks/CU (proven ~107 us structure).
// P3 writes per-wave PV partials straight to global (no LDS cross-wave red).
// P2/P4 are q0-per-b only.
// ===========================================================================
template<int CC>
__global__ __launch_bounds__(256, CC) void k_one(
        const float* __restrict__ X, const float* __restrict__ Wnode,
        const float* __restrict__ Wfix, const float* __restrict__ Wstep,
        const float* __restrict__ Wout, const int* __restrict__ prev,
        const int* __restrict__ first, const void* __restrict__ mask,
        int* __restrict__ syg, float* __restrict__ partial,
        float* __restrict__ qkg, float* __restrict__ sqw,
        float* __restrict__ pvp, float* __restrict__ gqg,
        float* __restrict__ esumg, float* __restrict__ out) {
    const int RC = NN / CC;
    const int bid = blockIdx.x, tid = threadIdx.x;
    const int b = bid / CC, ch = bid % CC;
    const int n0 = ch * RC;
    const size_t xoff = (size_t)b * NN * DD;
    int* sy = syg + b * 16;

    __shared__ __align__(16) float pool[1536];      // 6 KB overlaid: P1/P2/P4
    __shared__ __align__(16) float qks[HH * DD];    // 4 KB
    __shared__ float gqv[DD];
    __shared__ float lgl[256];
    __shared__ unsigned short cidxL[256];
    __shared__ float Sh[HH];
    __shared__ float redw[4];
    __shared__ int wbase[4];
    __shared__ int s_flag, s_cnt;

    // ---- P0: mask dtype detect ----
    if (tid < 64) {
        const unsigned int* mw = (const unsigned int*)mask;
        unsigned int a0 = mw[tid], a1 = mw[tid + 64], a2 = mw[tid + 128], a3 = mw[tid + 192];
        int ii = (a0 <= 1u) && (a1 <= 1u) && (a2 <= 1u) && (a3 <= 1u);
        int ff = (a0 == 0u || a0 == 0x3F800000u) && (a1 == 0u || a1 == 0x3F800000u) &&
                 (a2 == 0u || a2 == 0x3F800000u) && (a3 == 0u || a3 == 0x3F800000u);
        int ai = __all(ii), af = __all(ff);
        if (tid == 0) s_flag = ai ? 1 : (af ? 2 : 0);
    }

    // ---- P1a: mean partial over own chunk (the one HBM pass over X) ----
    {
        float4* red4 = (float4*)pool;               // [8][32]
        int c = tid & 31, s = tid >> 5;
        const float4* Xr = (const float4*)(X + xoff);
        float4 acc = make_float4(0.f, 0.f, 0.f, 0.f);
        for (int nl = s; nl < RC; nl += 8) {
            float4 v = Xr[(n0 + nl) * 32 + c];
            acc.x += v.x; acc.y += v.y; acc.z += v.z; acc.w += v.w;
        }
        red4[s * 32 + c] = acc;
        __syncthreads();
        for (int st = 4; st >= 1; st >>= 1) {
            if (s < st) {
                float4 o = red4[(s + st) * 32 + c];
                float4 r = red4[s * 32 + c];
                r.x += o.x; r.y += o.y; r.z += o.z; r.w += o.w;
                red4[s * 32 + c] = r;
            }
            __syncthreads();
        }
        if (s == 0) {
            float4 r = red4[c];
            float* outp = partial + ((size_t)b * CC + ch) * DD + 4 * c;
            outp[0] = r.x; outp[1] = r.y; outp[2] = r.z; outp[3] = r.w;
        }
    }
    // ---- P1b: compact own chunk's unmasked rows into LDS ----
    {
        int w = tid >> 6, lane = tid & 63;
        bool un = (tid < RC) && !get_mask(mask, s_flag, (size_t)b * NN + n0 + tid);
        unsigned long long bal = __ballot(un);
        if (lane == 0) wbase[w] = __popcll(bal);
        __syncthreads();
        int base = 0;
        for (int ww = 0; ww < w; ++ww) base += wbase[ww];
        int off = __popcll(bal & ((1ULL << lane) - 1ULL));
        if (un) cidxL[base + off] = (unsigned short)tid;
        if (tid == 0) s_cnt = wbase[0] + wbase[1] + wbase[2] + wbase[3];
    }
    __syncthreads();
    if (tid == 0) sy_arrive(&sy[SY_CNTA]);

    // ---- P2 (q0 only): mean -> query -> qk -> qkg ----
    if (ch == 0) {
        if (tid == 0) sy_wait(&sy[SY_CNTA], CC);
        __syncthreads();
        float* ge = pool;            // 128
        float* sc = pool + 128;      // 256
        float* qv = pool + 384;      // 128
        float* qp = pool + 512;      // 256
        if (tid < DD) {
            float g = 0.f;
            #pragma unroll
            for (int cc = 0; cc < CC; ++cc) g += partial[((size_t)b * CC + cc) * DD + tid];
            ge[tid] = g * (1.0f / NN);
        }
        {
            int src = (tid < DD) ? first[b] : prev[b];
            sc[tid] = X[xoff + (size_t)src * DD + (tid & 127)];
        }
        __syncthreads();
        int p = tid >> 7, d = tid & 127;
        {
            float a = 0.f;
            #pragma unroll 4
            for (int k = p * 64; k < p * 64 + 64; ++k)      a += ge[k] * Wfix[(size_t)k * DD + d];
            #pragma unroll 4
            for (int k = p * 128; k < p * 128 + 128; ++k)   a += sc[k] * Wstep[(size_t)k * DD + d];
            qp[p * DD + d] = a;
        }
        __syncthreads();
        if (tid < DD) qv[tid] = qp[tid] + qp[DD + tid];
        __syncthreads();
        {
            const float* wrow = Wnode + (size_t)d * 384;
            #pragma unroll
            for (int h = p * 4; h < p * 4 + 4; ++h) {
                const float4* wr = (const float4*)(wrow + h * 16);
                float a = 0.f;
                #pragma unroll
                for (int j4 = 0; j4 < 4; ++j4) {
                    float4 w = wr[j4];
                    a += w.x * qv[h * 16 + 4 * j4]     + w.y * qv[h * 16 + 4 * j4 + 1]
                       + w.z * qv[h * 16 + 4 * j4 + 2] + w.w * qv[h * 16 + 4 * j4 + 3];
                }
                qkg[((size_t)b * HH + h) * DD + d] = 0.25f * a;   // 1/sqrt(16)
            }
        }
        __syncthreads();
        if (tid == 0) sy_set(&sy[SY_QK]);
    }
    if (tid == 0) sy_wait(&sy[SY_QK], 1);
    __syncthreads();
    for (int i = tid; i < HH * DD; i += 256) qks[i] = qkg[(size_t)b * HH * DD + i];
    __syncthreads();

    // ---- P3: compat -> exp(no-max, clamp 80) -> PV, wave-rows, no LDS red ----
    {
        const int lane = tid & 63, w = tid >> 6;
        const int h = lane & 7, cg = lane >> 3;     // 8 col-groups of 16
        const int len = s_cnt;
        const int iters = (len + 3) >> 2;

        float4 qk0, qk1, qk2, qk3;
        {
            const float4* qr = (const float4*)&qks[h * DD + cg * 16];
            qk0 = qr[0]; qk1 = qr[1]; qk2 = qr[2]; qk3 = qr[3];
        }
        float acc[16];
        #pragma unroll
        for (int j = 0; j < 16; ++j) acc[j] = 0.f;
        float S = 0.f;

        for (int it = 0; it < iters; ++it) {
            int k = it * 4 + w;
            bool valid = (k < len);
            int kk = valid ? k : 0;
            int n = n0 + cidxL[kk];
            const float4* xr = (const float4*)(X + xoff + (size_t)n * DD + cg * 16);
            float4 v0 = xr[0], v1 = xr[1], v2 = xr[2], v3 = xr[3];
            float cp = v0.x * qk0.x + v0.y * qk0.y + v0.z * qk0.z + v0.w * qk0.w
                     + v1.x * qk1.x + v1.y * qk1.y + v1.z * qk1.z + v1.w * qk1.w
                     + v2.x * qk2.x + v2.y * qk2.y + v2.z * qk2.z + v2.w * qk2.w
                     + v3.x * qk3.x + v3.y * qk3.y + v3.z * qk3.z + v3.w * qk3.w;
            cp += __shfl_xor(cp, 8, 64);            // reduce over cg bits
            cp += __shfl_xor(cp, 16, 64);
            cp += __shfl_xor(cp, 32, 64);
            float pe = valid ? __expf(fminf(cp, 80.f)) : 0.f;
            S += pe;
            acc[0]  += pe * v0.x; acc[1]  += pe * v0.y; acc[2]  += pe * v0.z; acc[3]  += pe * v0.w;
            acc[4]  += pe * v1.x; acc[5]  += pe * v1.y; acc[6]  += pe * v1.z; acc[7]  += pe * v1.w;
            acc[8]  += pe * v2.x; acc[9]  += pe * v2.y; acc[10] += pe * v2.z; acc[11] += pe * v2.w;
            acc[12] += pe * v3.x; acc[13] += pe * v3.y; acc[14] += pe * v3.z; acc[15] += pe * v3.w;
        }
        // per-wave slot, straight to global
        const size_t slot = ((size_t)b * CC + ch) * 4 + w;
        float* dst = pvp + slot * (HH * DD) + h * DD + cg * 16;
        *((float4*)&dst[0])  = make_float4(acc[0],  acc[1],  acc[2],  acc[3]);
        *((float4*)&dst[4])  = make_float4(acc[4],  acc[5],  acc[6],  acc[7]);
        *((float4*)&dst[8])  = make_float4(acc[8],  acc[9],  acc[10], acc[11]);
        *((float4*)&dst[12]) = make_float4(acc[12], acc[13], acc[14], acc[15]);
        if (lane < 8) sqw[slot * HH + lane] = S;    // cg==0 lanes hold S[h]
    }
    __syncthreads();
    if (tid == 0) sy_arrive(&sy[SY_CNTC]);

    // ---- P4 (q0 only): combine 4*CC slots -> heads -> glimpse -> gq ----
    if (ch == 0) {
        if (tid == 0) sy_wait(&sy[SY_CNTC], CC);
        __syncthreads();
        float* xa = pool;            // 1024
        float* hd = pool + 1024;     // 128
        float* gl = pool + 1152;     // 128
        float* qp = pool + 1280;     // 256
        if (tid < HH) {
            float S = 0.f;
            for (int s = 0; s < CC * 4; ++s)
                S += sqw[((size_t)b * CC * 4 + s) * HH + tid];
            Sh[tid] = 1.0f / S;
        }
        __syncthreads();
        for (int idx = tid; idx < HH * DD; idx += 256) {
            float a = 0.f;
            for (int s = 0; s < CC * 4; ++s)
                a += pvp[((size_t)b * CC * 4 + s) * (HH * DD) + idx];
            xa[idx] = a * Sh[idx >> 7];
        }
        __syncthreads();
        int p = tid >> 7, t = tid & 127;
        {
            int h = t >> 4;
            float a = 0.f;
            #pragma unroll 4
            for (int d = p * 64; d < p * 64 + 64; ++d)
                a += xa[h * DD + d] * Wnode[(size_t)d * 384 + 128 + t];
            qp[p * DD + t] = a;
        }
        __syncthreads();
        if (tid < DD) hd[tid] = qp[tid] + qp[DD + tid];
        __syncthreads();
        {
            float a = 0.f;
            #pragma unroll 4
            for (int k = p * 64; k < p * 64 + 64; ++k) a += hd[k] * Wout[(size_t)k * DD + t];
            qp[p * DD + t] = a;
        }
        __syncthreads();
        if (tid < DD) gl[tid] = qp[tid] + qp[DD + tid];
        __syncthreads();
        {
            const float4* wr = (const float4*)(Wnode + (size_t)t * 384 + 256 + p * 64);
            float a = 0.f;
            #pragma unroll 4
            for (int j4 = 0; j4 < 16; ++j4) {
                float4 w = wr[j4];
                int k = p * 64 + 4 * j4;
                a += w.x * gl[k] + w.y * gl[k + 1] + w.z * gl[k + 2] + w.w * gl[k + 3];
            }
            qp[p * DD + t] = a;
        }
        __syncthreads();
        if (tid < DD)
            gqg[(size_t)b * DD + tid] = (qp[tid] + qp[DD + tid]) * 0.08838834764831845f;
        __syncthreads();
        if (tid == 0) sy_set(&sy[SY_GQ]);
    }
    if (tid == 0) sy_wait(&sy[SY_GQ], 1);
    __syncthreads();
    if (tid < DD) gqv[tid] = gqg[(size_t)b * DD + tid];
    for (int i = tid; i < RC; i += 256) lgl[i] = NEG;
    __syncthreads();

    // ---- P5: logits over compacted rows, exp-partials at fixed base 10 ----
    {
        const int len = s_cnt;
        const int iters = (len + 31) >> 5;
        int g = tid & 7, rr = tid >> 3;
        float esum = 0.f;
        for (int it = 0; it < iters; ++it) {
            int k = it * 32 + rr;
            bool valid = (k < len);
            int kk = valid ? k : 0;
            int nl = cidxL[kk];
            const float4* xr = (const float4*)(X + xoff + (size_t)(n0 + nl) * DD);
            float a = 0.f;
            #pragma unroll
            for (int i = 0; i < 4; ++i) {
                float4 v = xr[g + 8 * i];
                int col = 4 * (g + 8 * i);
                a += v.x * gqv[col] + v.y * gqv[col + 1]
                   + v.z * gqv[col + 2] + v.w * gqv[col + 3];
            }
            a += __shfl_xor(a, 1, 8);
            a += __shfl_xor(a, 2, 8);
            a += __shfl_xor(a, 4, 8);
            if (g == 0 && valid) {
                float l = 10.0f * tanhf(a);
                lgl[nl] = l;
                esum += __expf(l - 10.0f);          // logits <= 10 always
            }
        }
        #pragma unroll
        for (int off = 32; off >= 1; off >>= 1) esum += __shfl_xor(esum, off, 64);
        if ((tid & 63) == 0) redw[tid >> 6] = esum;
        __syncthreads();
        if (tid == 0) esumg[(size_t)b * CC + ch] = redw[0] + redw[1] + redw[2] + redw[3];
    }
    __syncthreads();
    if (tid == 0) { sy_arrive(&sy[SY_CNTE]); sy_wait(&sy[SY_CNTE], CC); }
    __syncthreads();

    // ---- P6: lse + store own chunk ----
    {
        float s = 0.f;
        for (int cc = 0; cc < CC; ++cc) s += esumg[(size_t)b * CC + cc];
        float lse = 10.0f + logf(s);
        for (int i = tid; i < RC; i += 256)
            out[(size_t)b * NN + n0 + i] = lgl[i] - lse;
    }
}

// ===========================================================================
// Fallback: proven mega-kernel (fp32), needs no workspace. (~108 us)
// ===========================================================================
__global__ __launch_bounds__(1024) void k_mega(
        const float* __restrict__ X, const float* __restrict__ Wnode,
        const float* __restrict__ Wfix, const float* __restrict__ Wstep,
        const float* __restrict__ Wout, const int* __restrict__ prev,
        const int* __restrict__ first, const void* __restrict__ mask,
        float* __restrict__ out) {
    int b = blockIdx.x, tid = threadIdx.x;
    __shared__ __align__(16) float cm[HH * 1024];
    __shared__ __align__(16) float qkl[HH * DD];
    __shared__ __align__(16) float qpart[8 * DD];
    __shared__ float xa[HH * DD];
    __shared__ float ge[DD], q[DD], sc[2 * DD], hd[DD], gl[DD], gqv[DD];
    __shared__ float red[16], invh[8];
    __shared__ int s_flag;
    const size_t xoff = (size_t)b * NN * DD;

    if (tid < 64) {
        const unsigned int* mw = (const unsigned int*)mask;
        unsigned int a0 = mw[tid], a1 = mw[tid + 64], a2 = mw[tid + 128], a3 = mw[tid + 192];
        int ii = (a0 <= 1u) && (a1 <= 1u) && (a2 <= 1u) && (a3 <= 1u);
        int ff = (a0 == 0u || a0 == 0x3F800000u) && (a1 == 0u || a1 == 0x3F800000u) &&
                 (a2 == 0u || a2 == 0x3F800000u) && (a3 == 0u || a3 == 0x3F800000u);
        int ai = __all(ii), af = __all(ff);
        if (tid == 0) s_flag = ai ? 1 : (af ? 2 : 0);
    }
    if (tid >= 256 && tid < 512) {
        int t = tid - 256;
        int src = (t < DD) ? first[b] : prev[b];
        sc[t] = X[xoff + (size_t)src * DD + (t & 127)];
    }
    {
        float4* red4 = (float4*)cm;
        int c = tid & 31, s = tid >> 5;
        const float4* Xr = (const float4*)(X + xoff);
        float4 acc = make_float4(0.f, 0.f, 0.f, 0.f);
        for (int n = s; n < NN; n += 32) {
            float4 v = Xr[n * 32 + c];
            acc.x += v.x; acc.y += v.y; acc.z += v.z; acc.w += v.w;
        }
        red4[s * 32 + c] = acc;
        __syncthreads();
        for (int st = 16; st >= 1; st >>= 1) {
            if (s < st) {
                float4 o = red4[(s + st) * 32 + c];
                float4 r = red4[s * 32 + c];
                r.x += o.x; r.y += o.y; r.z += o.z; r.w += o.w;
                red4[s * 32 + c] = r;
            }
            __syncthreads();
        }
        if (s == 0) {
            float4 r = red4[c];
            ge[4 * c] = r.x * (1.0f / NN); ge[4 * c + 1] = r.y * (1.0f / NN);
            ge[4 * c + 2] = r.z * (1.0f / NN); ge[4 * c + 3] = r.w * (1.0f / NN);
        }
        __syncthreads();
    }
    const int flag = s_flag;
    {
        int p = tid >> 7, d = tid & 127;
        float a = 0.f;
        for (int k = p * 16; k < p * 16 + 16; ++k) a += ge[k] * Wfix[k * DD + d];
        for (int k = p * 32; k < p * 32 + 32; ++k) a += sc[k] * Wstep[k * DD + d];
        qpart[p * DD + d] = a;
        __syncthreads();
        if (tid < DD) {
            float s = 0.f;
            for (int pp = 0; pp < 8; ++pp) s += qpart[pp * DD + tid];
            q[tid] = s;
        }
        __syncthreads();
        int d2 = tid >> 3, h = tid & 7;
        const float4* wr = (const float4*)(Wnode + (size_t)d2 * 384 + h * 16);
        float a2 = 0.f;
        for (int j4 = 0; j4 < 4; ++j4) {
            float4 w = wr[j4];
            a2 += w.x * q[h * 16 + 4 * j4]     + w.y * q[h * 16 + 4 * j4 + 1]
                + w.z * q[h * 16 + 4 * j4 + 2] + w.w * q[h * 16 + 4 * j4 + 3];
        }
        qkl[h * DD + d2] = 0.25f * a2;
        __syncthreads();
    }
    {
        int g = tid & 7;
        for (int it = 0; it < 8; ++it) {
            int n = it * 128 + (tid >> 3);
            if (n < NN) {
                float acc[HH] = {0.f, 0.f, 0.f, 0.f, 0.f, 0.f, 0.f, 0.f};
                const float4* xr = (const float4*)(X + xoff + (size_t)n * DD);
                for (int i = 0; i < 4; ++i) {
                    float4 v = xr[g + 8 * i];
                    int col = 4 * (g + 8 * i);
                    for (int h = 0; h < HH; ++h)
                        acc[h] += v.x * qkl[h * DD + col]     + v.y * qkl[h * DD + col + 1]
                                + v.z * qkl[h * DD + col + 2] + v.w * qkl[h * DD + col + 3];
                }
                for (int h = 0; h < HH; ++h) {
                    acc[h] += __shfl_xor(acc[h], 1, 8);
                    acc[h] += __shfl_xor(acc[h], 2, 8);
                    acc[h] += __shfl_xor(acc[h], 4, 8);
                }
                float val = acc[0];
                for (int h = 1; h < HH; ++h) val = (g == h) ? acc[h] : val;
                bool mk = get_mask(mask, flag, (size_t)b * NN + n);
                cm[g * 1024 + n] = mk ? NEG : val;
            }
        }
        __syncthreads();
    }
    {
        int h = tid >> 7, lane = tid & 127;
        float mx = -INFINITY;
        for (int n = lane; n < NN; n += 128) mx = fmaxf(mx, cm[h * 1024 + n]);
        for (int off = 32; off >= 1; off >>= 1) mx = fmaxf(mx, __shfl_xor(mx, off, 64));
        if ((tid & 63) == 0) red[tid >> 6] = mx;
        __syncthreads();
        float m_h = fmaxf(red[2 * h], red[2 * h + 1]);
        float sm = 0.f;
        for (int n = lane; n < NN; n += 128) {
            float p = __expf(cm[h * 1024 + n] - m_h);
            cm[h * 1024 + n] = p;
            sm += p;
        }
        for (int off = 32; off >= 1; off >>= 1) sm += __shfl_xor(sm, off, 64);
        __syncthreads();
        if ((tid & 63) == 0) red[tid >> 6] = sm;
        __syncthreads();
        if (tid < HH) invh[tid] = 1.0f / (red[2 * tid] + red[2 * tid + 1]);
        __syncthreads();
    }
    {
        int s = tid >> 7, d = tid & 127;
        float acc[HH] = {0.f, 0.f, 0.f, 0.f, 0.f, 0.f, 0.f, 0.f};
        for (int n = s; n < NN; n += 8) {
            float x = X[xoff + (size_t)n * DD + d];
            for (int h = 0; h < HH; ++h) acc[h] += cm[h * 1024 + n] * x;
        }
        __syncthreads();
        float* xp = cm;
        for (int h = 0; h < HH; ++h) xp[(s * HH + h) * DD + d] = acc[h];
        __syncthreads();
        if (s == 0) {
            for (int h = 0; h < HH; ++h) {
                float t = 0.f;
                for (int ss = 0; ss < 8; ++ss) t += xp[(ss * HH + h) * DD + d];
                xa[h * DD + d] = t * invh[h];
            }
        }
        __syncthreads();
    }
    {
        int p = tid >> 7, t = tid & 127;
        int h = t >> 4;
        float a = 0.f;
        for (int d = p * 16; d < p * 16 + 16; ++d)
            a += xa[h * DD + d] * Wnode[(size_t)d * 384 + 128 + t];
        qpart[p * DD + t] = a;
        __syncthreads();
        if (tid < DD) {
            float s = 0.f;
            for (int pp = 0; pp < 8; ++pp) s += qpart[pp * DD + tid];
            hd[tid] = s;
        }
        __syncthreads();
        a = 0.f;
        for (int k = p * 16; k < p * 16 + 16; ++k) a += hd[k] * Wout[(size_t)k * DD + t];
        qpart[p * DD + t] = a;
        __syncthreads();
        if (tid < DD) {
            float s = 0.f;
            for (int pp = 0; pp < 8; ++pp) s += qpart[pp * DD + tid];
            gl[tid] = s;
        }
        __syncthreads();
        const float4* wr = (const float4*)(Wnode + (size_t)t * 384 + 256 + p * 16);
        a = 0.f;
        for (int j4 = 0; j4 < 4; ++j4) {
            float4 w = wr[j4];
            int k = p * 16 + 4 * j4;
            a += w.x * gl[k] + w.y * gl[k + 1] + w.z * gl[k + 2] + w.w * gl[k + 3];
        }
        qpart[p * DD + t] = a;
        __syncthreads();
        if (tid < DD) {
            float s = 0.f;
            for (int pp = 0; pp < 8; ++pp) s += qpart[pp * DD + tid];
            gqv[tid] = s * 0.08838834764831845f;
        }
        __syncthreads();
    }
    {
        float* lg = qkl;
        int g = tid & 7;
        for (int it = 0; it < 8; ++it) {
            int n = it * 128 + (tid >> 3);
            if (n < NN) {
                const float4* xr = (const float4*)(X + xoff + (size_t)n * DD);
                float a = 0.f;
                for (int i = 0; i < 4; ++i) {
                    float4 v = xr[g + 8 * i];
                    int col = 4 * (g + 8 * i);
                    a += v.x * gqv[col] + v.y * gqv[col + 1] + v.z * gqv[col + 2] + v.w * gqv[col + 3];
                }
                a += __shfl_xor(a, 1, 8);
                a += __shfl_xor(a, 2, 8);
                a += __shfl_xor(a, 4, 8);
                if (g == 0) {
                    float lgt = 10.0f * tanhf(a);
                    lg[n] = get_mask(mask, flag, (size_t)b * NN + n) ? NEG : lgt;
                }
            }
        }
        __syncthreads();
        float v = (tid < NN) ? lg[tid] : -INFINITY;
        float mx = v;
        for (int off = 32; off >= 1; off >>= 1) mx = fmaxf(mx, __shfl_xor(mx, off, 64));
        if ((tid & 63) == 0) red[tid >> 6] = mx;
        __syncthreads();
        float m = red[0];
        for (int w = 1; w < 16; ++w) m = fmaxf(m, red[w]);
        float e = (tid < NN) ? __expf(v - m) : 0.f;
        float sm = e;
        for (int off = 32; off >= 1; off >>= 1) sm += __shfl_xor(sm, off, 64);
        __syncthreads();
        if ((tid & 63) == 0) red[tid >> 6] = sm;
        __syncthreads();
        float s2 = 0.f;
        for (int w = 0; w < 16; ++w) s2 += red[w];
        float lse = m + logf(s2);
        if (tid < NN) out[(size_t)b * NN + tid] = v - lse;
    }
}

// ---------------------------------------------------------------------------
extern "C" void kernel_launch(void* const* d_in, const int* in_sizes, int n_in,
                              void* d_out, int out_size, void* d_ws, size_t ws_size,
                              hipStream_t stream) {
    const float* X     = (const float*)d_in[0];
    const float* Wnode = (const float*)d_in[1];
    const float* Wfix  = (const float*)d_in[2];
    const float* Wstep = (const float*)d_in[3];
    const float* Wout  = (const float*)d_in[4];
    const int*   prev  = (const int*)d_in[5];
    const int*   first = (const int*)d_in[6];
    const void*  mask  = d_in[7];
    float* out = (float*)d_out;

    // layout sized for CC=8 (CC=4 uses a subset)
    char* wsb = (char*)d_ws;
    int*   syg     = (int*)wsb;                              // 16 KB
    float* partial = (float*)(wsb + 16384);                  // B*8*D    = 262144 f
    float* qkg     = partial + (size_t)BB * 8 * DD;          // B*H*D    = 262144 f
    float* sqw     = qkg + (size_t)BB * HH * DD;             // B*8*4*H  = 65536 f
    float* pvp     = sqw + (size_t)BB * 8 * 4 * HH;          // B*8*4*H*D= 8388608 f
    float* gqg     = pvp + (size_t)BB * 8 * 4 * HH * DD;     // B*D      = 32768 f
    float* esumg   = gqg + (size_t)BB * DD;                  // B*8      = 2048 f
    const size_t need = 16384 + sizeof(float) * (
        (size_t)BB * 8 * DD + (size_t)BB * HH * DD + (size_t)BB * 8 * 4 * HH +
        (size_t)BB * 8 * 4 * HH * DD + (size_t)BB * DD + (size_t)BB * 8);

    int maxb8 = 0, maxb4 = 0;
    bool ws_ok = (ws_size >= need);
    if (ws_ok) {
        hipOccupancyMaxActiveBlocksPerMultiprocessor(&maxb8, (const void*)k_one<8>, 256, 0);
        hipOccupancyMaxActiveBlocksPerMultiprocessor(&maxb4, (const void*)k_one<4>, 256, 0);
    }
    if (ws_ok && maxb8 >= 8) {
        hipMemsetAsync(syg, 0, 16384, stream);
        k_one<8><<<BB * 8, 256, 0, stream>>>(X, Wnode, Wfix, Wstep, Wout, prev, first,
                                             mask, syg, partial, qkg, sqw, pvp, gqg,
                                             esumg, out);
    } else if (ws_ok && maxb4 >= 4) {
        hipMemsetAsync(syg, 0, 16384, stream);
        k_one<4><<<BB * 4, 256, 0, stream>>>(X, Wnode, Wfix, Wstep, Wout, prev, first,
                                             mask, syg, partial, qkg, sqw, pvp, gqg,
                                             esumg, out);
    } else {
        k_mega<<<BB, 1024, 0, stream>>>(X, Wnode, Wfix, Wstep, Wout,
                                        prev, first, mask, out);
    }
}

// Round 18
// 107.267 us; speedup vs baseline: 1.0021x; 1.0021x over previous
//
#include <hip/hip_runtime.h>
#include <math.h>

#define BB 256
#define NN 1000
#define DD 128
#define HH 8
#define QQ 4            // sibling blocks per batch element
#define RQ 250          // rows per quarter
#define NEG -1e9f

#define SY_CNTA 0
#define SY_CNTC 1
#define SY_CNTE 2

__device__ __forceinline__ bool get_mask(const void* m, int flag, size_t idx) {
    if (flag == 1) return ((const int*)m)[idx] != 0;
    if (flag == 2) return ((const float*)m)[idx] != 0.0f;
    return ((const unsigned char*)m)[idx] != 0;
}

__device__ __forceinline__ void sy_barrier(int* p, int tid, int tgt) {
    if (tid == 0) {
        __builtin_amdgcn_fence(__ATOMIC_RELEASE, "agent");
        __hip_atomic_fetch_add(p, 1, __ATOMIC_RELAXED, __HIP_MEMORY_SCOPE_AGENT);
        while (__hip_atomic_load(p, __ATOMIC_RELAXED, __HIP_MEMORY_SCOPE_AGENT) < tgt)
            __builtin_amdgcn_s_sleep(8);
        __builtin_amdgcn_fence(__ATOMIC_ACQUIRE, "agent");
    }
    __syncthreads();
}

// ===========================================================================
// Round-15 structure; ONLY change: P1a mean loop is 4x unrolled with 4
// independent loads + accumulators (maximize memory-level parallelism on
// the single HBM pass over X).
// ===========================================================================
__global__ __launch_bounds__(256, 4) void k_one(
        const float* __restrict__ X, const float* __restrict__ Wnode,
        const float* __restrict__ Wfix, const float* __restrict__ Wstep,
        const float* __restrict__ Wout, const int* __restrict__ prev,
        const int* __restrict__ first, const void* __restrict__ mask,
        int* __restrict__ syg, float* __restrict__ partial,
        float* __restrict__ sqw, float* __restrict__ pvp,
        float* __restrict__ esumg, float* __restrict__ out) {
    const int bid = blockIdx.x, tid = threadIdx.x;
    const int b = bid >> 2, q = bid & 3;
    const int n0 = q * RQ;
    const size_t xoff = (size_t)b * NN * DD;
    int* sy = syg + b * 16;

    __shared__ __align__(16) float pool[4096];      // 16 KB phase-overlaid
    __shared__ __align__(16) float qks[HH][DD];     // 4 KB  (P2 -> P3)
    __shared__ float gqv[DD];                       // P4 -> P5
    __shared__ float lgl[256];                      // P5 -> P6
    __shared__ unsigned short cidxL[256];
    __shared__ float redS[4][HH];
    __shared__ float Sh[HH];
    __shared__ float redw[4];
    __shared__ int wbase[4];
    __shared__ int s_flag, s_cnt;

    // ---- P0: mask dtype detect (local, cheap) ----
    if (tid < 64) {
        const unsigned int* mw = (const unsigned int*)mask;
        unsigned int a0 = mw[tid], a1 = mw[tid + 64], a2 = mw[tid + 128], a3 = mw[tid + 192];
        int ii = (a0 <= 1u) && (a1 <= 1u) && (a2 <= 1u) && (a3 <= 1u);
        int ff = (a0 == 0u || a0 == 0x3F800000u) && (a1 == 0u || a1 == 0x3F800000u) &&
                 (a2 == 0u || a2 == 0x3F800000u) && (a3 == 0u || a3 == 0x3F800000u);
        int ai = __all(ii), af = __all(ff);
        if (tid == 0) s_flag = ai ? 1 : (af ? 2 : 0);
    }

    // ---- P1a: mean partial over own quarter — 4x MLP unroll ----
    {
        float4* red4 = (float4*)pool;               // [8][32]
        int c = tid & 31, s = tid >> 5;
        const float4* Xr = (const float4*)(X + xoff);
        float4 a0 = make_float4(0.f, 0.f, 0.f, 0.f);
        float4 a1 = make_float4(0.f, 0.f, 0.f, 0.f);
        float4 a2 = make_float4(0.f, 0.f, 0.f, 0.f);
        float4 a3 = make_float4(0.f, 0.f, 0.f, 0.f);
        int nl = s;
        for (; nl + 24 < RQ; nl += 32) {            // 4 independent loads/iter
            float4 v0 = Xr[(n0 + nl) * 32 + c];
            float4 v1 = Xr[(n0 + nl + 8) * 32 + c];
            float4 v2 = Xr[(n0 + nl + 16) * 32 + c];
            float4 v3 = Xr[(n0 + nl + 24) * 32 + c];
            a0.x += v0.x; a0.y += v0.y; a0.z += v0.z; a0.w += v0.w;
            a1.x += v1.x; a1.y += v1.y; a1.z += v1.z; a1.w += v1.w;
            a2.x += v2.x; a2.y += v2.y; a2.z += v2.z; a2.w += v2.w;
            a3.x += v3.x; a3.y += v3.y; a3.z += v3.z; a3.w += v3.w;
        }
        for (; nl < RQ; nl += 8) {                  // tail
            float4 v = Xr[(n0 + nl) * 32 + c];
            a0.x += v.x; a0.y += v.y; a0.z += v.z; a0.w += v.w;
        }
        float4 acc = make_float4(a0.x + a1.x + a2.x + a3.x,
                                 a0.y + a1.y + a2.y + a3.y,
                                 a0.z + a1.z + a2.z + a3.z,
                                 a0.w + a1.w + a2.w + a3.w);
        red4[s * 32 + c] = acc;
        __syncthreads();
        for (int st = 4; st >= 1; st >>= 1) {
            if (s < st) {
                float4 o = red4[(s + st) * 32 + c];
                float4 r = red4[s * 32 + c];
                r.x += o.x; r.y += o.y; r.z += o.z; r.w += o.w;
                red4[s * 32 + c] = r;
            }
            __syncthreads();
        }
        if (s == 0) {
            float4 r = red4[c];
            float* outp = partial + ((size_t)b * QQ + q) * DD + 4 * c;
            outp[0] = r.x; outp[1] = r.y; outp[2] = r.z; outp[3] = r.w;
        }
    }
    // ---- P1b: compact own quarter's unmasked rows into LDS ----
    {
        int w = tid >> 6, lane = tid & 63;
        bool un = (tid < RQ) && !get_mask(mask, s_flag, (size_t)b * NN + n0 + tid);
        unsigned long long bal = __ballot(un);
        if (lane == 0) wbase[w] = __popcll(bal);
        __syncthreads();
        int base = 0;
        for (int ww = 0; ww < w; ++ww) base += wbase[ww];
        int off = __popcll(bal & ((1ULL << lane) - 1ULL));
        if (un) cidxL[base + off] = (unsigned short)tid;
        if (tid == 0) s_cnt = wbase[0] + wbase[1] + wbase[2] + wbase[3];
    }
    __syncthreads();
    sy_barrier(&sy[SY_CNTA], tid, QQ);

    // ---- P2 (ALL blocks, redundant): mean -> query -> qks[8][128] in LDS ----
    {
        float* ge = pool;            // 128
        float* sc = pool + 128;      // 256
        float* qv = pool + 384;      // 128
        float* qp = pool + 512;      // 256
        if (tid < DD) {
            float g = 0.f;
            #pragma unroll
            for (int qq = 0; qq < QQ; ++qq) g += partial[((size_t)b * QQ + qq) * DD + tid];
            ge[tid] = g * (1.0f / NN);
        }
        {
            int src = (tid < DD) ? first[b] : prev[b];
            sc[tid] = X[xoff + (size_t)src * DD + (tid & 127)];
        }
        __syncthreads();
        int p = tid >> 7, d = tid & 127;
        {
            float a = 0.f;
            #pragma unroll 8
            for (int k = p * 64; k < p * 64 + 64; ++k)      a += ge[k] * Wfix[(size_t)k * DD + d];
            #pragma unroll 8
            for (int k = p * 128; k < p * 128 + 128; ++k)   a += sc[k] * Wstep[(size_t)k * DD + d];
            qp[p * DD + d] = a;
        }
        __syncthreads();
        if (tid < DD) qv[tid] = qp[tid] + qp[DD + tid];
        __syncthreads();
        {
            const float* wrow = Wnode + (size_t)d * 384;
            #pragma unroll
            for (int h = p * 4; h < p * 4 + 4; ++h) {
                const float4* wr = (const float4*)(wrow + h * 16);
                float a = 0.f;
                #pragma unroll
                for (int j4 = 0; j4 < 4; ++j4) {
                    float4 w = wr[j4];
                    a += w.x * qv[h * 16 + 4 * j4]     + w.y * qv[h * 16 + 4 * j4 + 1]
                       + w.z * qv[h * 16 + 4 * j4 + 2] + w.w * qv[h * 16 + 4 * j4 + 3];
                }
                qks[h][d] = 0.25f * a;              // 1/sqrt(16)
            }
        }
        __syncthreads();
    }

    // ---- P3: compat -> exp(no-max, clamp 80) -> PV. 32 lanes/row, acc[8][4] ----
    {
        float* redpv = pool;                        // [4][8][128] = 16 KB
        const int g = tid & 31, r = tid >> 5, w = tid >> 6;
        const int len = s_cnt;
        const int iters = (len + 7) >> 3;
        float acc[HH][4];
        #pragma unroll
        for (int h = 0; h < HH; ++h) {
            acc[h][0] = 0.f; acc[h][1] = 0.f; acc[h][2] = 0.f; acc[h][3] = 0.f;
        }
        float S[HH] = {0.f, 0.f, 0.f, 0.f, 0.f, 0.f, 0.f, 0.f};

        for (int it = 0; it < iters; ++it) {
            int k = it * 8 + r;
            bool valid = (k < len);
            int kk = valid ? k : (len - 1);         // len>=1 when iters>0
            int n = n0 + cidxL[kk];
            float4 v = *(const float4*)(X + xoff + (size_t)n * DD + 4 * g);
            float cp[HH];
            #pragma unroll
            for (int h = 0; h < HH; ++h) {
                cp[h] = v.x * qks[h][4 * g]     + v.y * qks[h][4 * g + 1]
                      + v.z * qks[h][4 * g + 2] + v.w * qks[h][4 * g + 3];
            }
            #pragma unroll
            for (int h = 0; h < HH; ++h) {
                cp[h] += __shfl_xor(cp[h], 1, 32);
                cp[h] += __shfl_xor(cp[h], 2, 32);
                cp[h] += __shfl_xor(cp[h], 4, 32);
                cp[h] += __shfl_xor(cp[h], 8, 32);
                cp[h] += __shfl_xor(cp[h], 16, 32);
            }
            #pragma unroll
            for (int h = 0; h < HH; ++h) {
                float pe = valid ? __expf(fminf(cp[h], 80.f)) : 0.f;
                S[h] += pe;
                acc[h][0] += pe * v.x; acc[h][1] += pe * v.y;
                acc[h][2] += pe * v.z; acc[h][3] += pe * v.w;
            }
        }
        // cross-slot reduce within wave (lane^32)
        #pragma unroll
        for (int h = 0; h < HH; ++h) {
            S[h] += __shfl_xor(S[h], 32, 64);
            acc[h][0] += __shfl_xor(acc[h][0], 32, 64);
            acc[h][1] += __shfl_xor(acc[h][1], 32, 64);
            acc[h][2] += __shfl_xor(acc[h][2], 32, 64);
            acc[h][3] += __shfl_xor(acc[h][3], 32, 64);
        }
        if ((tid & 63) < 32) {
            #pragma unroll
            for (int h = 0; h < HH; ++h)
                *((float4*)&redpv[((size_t)w * HH + h) * DD + 4 * g]) =
                    make_float4(acc[h][0], acc[h][1], acc[h][2], acc[h][3]);
            if (g == 0) {
                #pragma unroll
                for (int h = 0; h < HH; ++h) redS[w][h] = S[h];
            }
        }
        __syncthreads();
        for (int idx = tid; idx < HH * DD; idx += 256) {
            int h = idx >> 7, d = idx & 127;
            pvp[(((size_t)b * QQ + q) * HH + h) * DD + d] =
                redpv[(0 * HH + h) * DD + d] + redpv[(1 * HH + h) * DD + d] +
                redpv[(2 * HH + h) * DD + d] + redpv[(3 * HH + h) * DD + d];
        }
        if (tid < HH)
            sqw[((size_t)b * QQ + q) * HH + tid] =
                redS[0][tid] + redS[1][tid] + redS[2][tid] + redS[3][tid];
    }
    __syncthreads();
    sy_barrier(&sy[SY_CNTC], tid, QQ);

    // ---- P4 (ALL blocks, redundant): combine -> heads -> glimpse -> gq ----
    {
        float* xa = pool;            // 1024
        float* hd = pool + 1024;     // 128
        float* gl = pool + 1152;     // 128
        float* qp = pool + 1280;     // 256
        if (tid < HH) {
            float S = 0.f;
            #pragma unroll
            for (int qq = 0; qq < QQ; ++qq) S += sqw[((size_t)b * QQ + qq) * HH + tid];
            Sh[tid] = 1.0f / S;
        }
        if (tid < RQ) lgl[tid] = NEG;
        __syncthreads();
        for (int idx = tid; idx < HH * DD; idx += 256) {
            int h = idx >> 7, d = idx & 127;
            float a = 0.f;
            #pragma unroll
            for (int qq = 0; qq < QQ; ++qq)
                a += pvp[(((size_t)b * QQ + qq) * HH + h) * DD + d];
            xa[h * DD + d] = a * Sh[h];
        }
        __syncthreads();
        int p = tid >> 7, t = tid & 127;
        {
            int h = t >> 4;
            float a = 0.f;
            #pragma unroll 8
            for (int d = p * 64; d < p * 64 + 64; ++d)
                a += xa[h * DD + d] * Wnode[(size_t)d * 384 + 128 + t];
            qp[p * DD + t] = a;
        }
        __syncthreads();
        if (tid < DD) hd[tid] = qp[tid] + qp[DD + tid];
        __syncthreads();
        {
            float a = 0.f;
            #pragma unroll 8
            for (int k = p * 64; k < p * 64 + 64; ++k) a += hd[k] * Wout[(size_t)k * DD + t];
            qp[p * DD + t] = a;
        }
        __syncthreads();
        if (tid < DD) gl[tid] = qp[tid] + qp[DD + tid];
        __syncthreads();
        {
            const float4* wr = (const float4*)(Wnode + (size_t)t * 384 + 256 + p * 64);
            float a = 0.f;
            #pragma unroll
            for (int j4 = 0; j4 < 16; ++j4) {
                float4 w = wr[j4];
                int k = p * 64 + 4 * j4;
                a += w.x * gl[k] + w.y * gl[k + 1] + w.z * gl[k + 2] + w.w * gl[k + 3];
            }
            qp[p * DD + t] = a;
        }
        __syncthreads();
        if (tid < DD) gqv[tid] = (qp[tid] + qp[DD + tid]) * 0.08838834764831845f;
        __syncthreads();
    }

    // ---- P5: logits over compacted rows, exp-partials at fixed base 10 ----
    {
        const int len = s_cnt;
        const int iters = (len + 31) >> 5;
        int g = tid & 7, rr = tid >> 3;
        float esum = 0.f;
        for (int it = 0; it < iters; ++it) {
            int k = it * 32 + rr;
            bool valid = (k < len);
            int kk = valid ? k : (len - 1);
            int nl = cidxL[kk];
            const float4* xr = (const float4*)(X + xoff + (size_t)(n0 + nl) * DD);
            float a = 0.f;
            #pragma unroll
            for (int i = 0; i < 4; ++i) {
                float4 v = xr[g + 8 * i];
                int col = 4 * (g + 8 * i);
                a += v.x * gqv[col] + v.y * gqv[col + 1]
                   + v.z * gqv[col + 2] + v.w * gqv[col + 3];
            }
            a += __shfl_xor(a, 1, 8);
            a += __shfl_xor(a, 2, 8);
            a += __shfl_xor(a, 4, 8);
            if (g == 0 && valid) {
                float l = 10.0f * tanhf(a);
                lgl[nl] = l;
                esum += __expf(l - 10.0f);          // logits <= 10 always
            }
        }
        #pragma unroll
        for (int off = 32; off >= 1; off >>= 1) esum += __shfl_xor(esum, off, 64);
        if ((tid & 63) == 0) redw[tid >> 6] = esum;
        __syncthreads();
        if (tid == 0) esumg[(size_t)b * QQ + q] = redw[0] + redw[1] + redw[2] + redw[3];
    }
    __syncthreads();
    sy_barrier(&sy[SY_CNTE], tid, QQ);

    // ---- P6: lse + store own quarter ----
    {
        float s = esumg[(size_t)b * QQ] + esumg[(size_t)b * QQ + 1]
                + esumg[(size_t)b * QQ + 2] + esumg[(size_t)b * QQ + 3];
        float lse = 10.0f + logf(s);
        if (tid < RQ) out[(size_t)b * NN + n0 + tid] = lgl[tid] - lse;
    }
}

// ===========================================================================
// Fallback: proven mega-kernel (fp32), needs no workspace. (~108 us)
// ===========================================================================
__global__ __launch_bounds__(1024) void k_mega(
        const float* __restrict__ X, const float* __restrict__ Wnode,
        const float* __restrict__ Wfix, const float* __restrict__ Wstep,
        const float* __restrict__ Wout, const int* __restrict__ prev,
        const int* __restrict__ first, const void* __restrict__ mask,
        float* __restrict__ out) {
    int b = blockIdx.x, tid = threadIdx.x;
    __shared__ __align__(16) float cm[HH * 1024];
    __shared__ __align__(16) float qkl[HH * DD];
    __shared__ __align__(16) float qpart[8 * DD];
    __shared__ float xa[HH * DD];
    __shared__ float ge[DD], q[DD], sc[2 * DD], hd[DD], gl[DD], gqv[DD];
    __shared__ float red[16], invh[8];
    __shared__ int s_flag;
    const size_t xoff = (size_t)b * NN * DD;

    if (tid < 64) {
        const unsigned int* mw = (const unsigned int*)mask;
        unsigned int a0 = mw[tid], a1 = mw[tid + 64], a2 = mw[tid + 128], a3 = mw[tid + 192];
        int ii = (a0 <= 1u) && (a1 <= 1u) && (a2 <= 1u) && (a3 <= 1u);
        int ff = (a0 == 0u || a0 == 0x3F800000u) && (a1 == 0u || a1 == 0x3F800000u) &&
                 (a2 == 0u || a2 == 0x3F800000u) && (a3 == 0u || a3 == 0x3F800000u);
        int ai = __all(ii), af = __all(ff);
        if (tid == 0) s_flag = ai ? 1 : (af ? 2 : 0);
    }
    if (tid >= 256 && tid < 512) {
        int t = tid - 256;
        int src = (t < DD) ? first[b] : prev[b];
        sc[t] = X[xoff + (size_t)src * DD + (t & 127)];
    }
    {
        float4* red4 = (float4*)cm;
        int c = tid & 31, s = tid >> 5;
        const float4* Xr = (const float4*)(X + xoff);
        float4 acc = make_float4(0.f, 0.f, 0.f, 0.f);
        for (int n = s; n < NN; n += 32) {
            float4 v = Xr[n * 32 + c];
            acc.x += v.x; acc.y += v.y; acc.z += v.z; acc.w += v.w;
        }
        red4[s * 32 + c] = acc;
        __syncthreads();
        for (int st = 16; st >= 1; st >>= 1) {
            if (s < st) {
                float4 o = red4[(s + st) * 32 + c];
                float4 r = red4[s * 32 + c];
                r.x += o.x; r.y += o.y; r.z += o.z; r.w += o.w;
                red4[s * 32 + c] = r;
            }
            __syncthreads();
        }
        if (s == 0) {
            float4 r = red4[c];
            ge[4 * c] = r.x * (1.0f / NN); ge[4 * c + 1] = r.y * (1.0f / NN);
            ge[4 * c + 2] = r.z * (1.0f / NN); ge[4 * c + 3] = r.w * (1.0f / NN);
        }
        __syncthreads();
    }
    const int flag = s_flag;
    {
        int p = tid >> 7, d = tid & 127;
        float a = 0.f;
        for (int k = p * 16; k < p * 16 + 16; ++k) a += ge[k] * Wfix[k * DD + d];
        for (int k = p * 32; k < p * 32 + 32; ++k) a += sc[k] * Wstep[k * DD + d];
        qpart[p * DD + d] = a;
        __syncthreads();
        if (tid < DD) {
            float s = 0.f;
            for (int pp = 0; pp < 8; ++pp) s += qpart[pp * DD + tid];
            q[tid] = s;
        }
        __syncthreads();
        int d2 = tid >> 3, h = tid & 7;
        const float4* wr = (const float4*)(Wnode + (size_t)d2 * 384 + h * 16);
        float a2 = 0.f;
        for (int j4 = 0; j4 < 4; ++j4) {
            float4 w = wr[j4];
            a2 += w.x * q[h * 16 + 4 * j4]     + w.y * q[h * 16 + 4 * j4 + 1]
                + w.z * q[h * 16 + 4 * j4 + 2] + w.w * q[h * 16 + 4 * j4 + 3];
        }
        qkl[h * DD + d2] = 0.25f * a2;
        __syncthreads();
    }
    {
        int g = tid & 7;
        for (int it = 0; it < 8; ++it) {
            int n = it * 128 + (tid >> 3);
            if (n < NN) {
                float acc[HH] = {0.f, 0.f, 0.f, 0.f, 0.f, 0.f, 0.f, 0.f};
                const float4* xr = (const float4*)(X + xoff + (size_t)n * DD);
                for (int i = 0; i < 4; ++i) {
                    float4 v = xr[g + 8 * i];
                    int col = 4 * (g + 8 * i);
                    for (int h = 0; h < HH; ++h)
                        acc[h] += v.x * qkl[h * DD + col]     + v.y * qkl[h * DD + col + 1]
                                + v.z * qkl[h * DD + col + 2] + v.w * qkl[h * DD + col + 3];
                }
                for (int h = 0; h < HH; ++h) {
                    acc[h] += __shfl_xor(acc[h], 1, 8);
                    acc[h] += __shfl_xor(acc[h], 2, 8);
                    acc[h] += __shfl_xor(acc[h], 4, 8);
                }
                float val = acc[0];
                for (int h = 1; h < HH; ++h) val = (g == h) ? acc[h] : val;
                bool mk = get_mask(mask, flag, (size_t)b * NN + n);
                cm[g * 1024 + n] = mk ? NEG : val;
            }
        }
        __syncthreads();
    }
    {
        int h = tid >> 7, lane = tid & 127;
        float mx = -INFINITY;
        for (int n = lane; n < NN; n += 128) mx = fmaxf(mx, cm[h * 1024 + n]);
        for (int off = 32; off >= 1; off >>= 1) mx = fmaxf(mx, __shfl_xor(mx, off, 64));
        if ((tid & 63) == 0) red[tid >> 6] = mx;
        __syncthreads();
        float m_h = fmaxf(red[2 * h], red[2 * h + 1]);
        float sm = 0.f;
        for (int n = lane; n < NN; n += 128) {
            float p = __expf(cm[h * 1024 + n] - m_h);
            cm[h * 1024 + n] = p;
            sm += p;
        }
        for (int off = 32; off >= 1; off >>= 1) sm += __shfl_xor(sm, off, 64);
        __syncthreads();
        if ((tid & 63) == 0) red[tid >> 6] = sm;
        __syncthreads();
        if (tid < HH) invh[tid] = 1.0f / (red[2 * tid] + red[2 * tid + 1]);
        __syncthreads();
    }
    {
        int s = tid >> 7, d = tid & 127;
        float acc[HH] = {0.f, 0.f, 0.f, 0.f, 0.f, 0.f, 0.f, 0.f};
        for (int n = s; n < NN; n += 8) {
            float x = X[xoff + (size_t)n * DD + d];
            for (int h = 0; h < HH; ++h) acc[h] += cm[h * 1024 + n] * x;
        }
        __syncthreads();
        float* xp = cm;
        for (int h = 0; h < HH; ++h) xp[(s * HH + h) * DD + d] = acc[h];
        __syncthreads();
        if (s == 0) {
            for (int h = 0; h < HH; ++h) {
                float t = 0.f;
                for (int ss = 0; ss < 8; ++ss) t += xp[(ss * HH + h) * DD + d];
                xa[h * DD + d] = t * invh[h];
            }
        }
        __syncthreads();
    }
    {
        int p = tid >> 7, t = tid & 127;
        int h = t >> 4;
        float a = 0.f;
        for (int d = p * 16; d < p * 16 + 16; ++d)
            a += xa[h * DD + d] * Wnode[(size_t)d * 384 + 128 + t];
        qpart[p * DD + t] = a;
        __syncthreads();
        if (tid < DD) {
            float s = 0.f;
            for (int pp = 0; pp < 8; ++pp) s += qpart[pp * DD + tid];
            hd[tid] = s;
        }
        __syncthreads();
        a = 0.f;
        for (int k = p * 16; k < p * 16 + 16; ++k) a += hd[k] * Wout[(size_t)k * DD + t];
        qpart[p * DD + t] = a;
        __syncthreads();
        if (tid < DD) {
            float s = 0.f;
            for (int pp = 0; pp < 8; ++pp) s += qpart[pp * DD + tid];
            gl[tid] = s;
        }
        __syncthreads();
        const float4* wr = (const float4*)(Wnode + (size_t)t * 384 + 256 + p * 16);
        a = 0.f;
        for (int j4 = 0; j4 < 4; ++j4) {
            float4 w = wr[j4];
            int k = p * 16 + 4 * j4;
            a += w.x * gl[k] + w.y * gl[k + 1] + w.z * gl[k + 2] + w.w * gl[k + 3];
        }
        qpart[p * DD + t] = a;
        __syncthreads();
        if (tid < DD) {
            float s = 0.f;
            for (int pp = 0; pp < 8; ++pp) s += qpart[pp * DD + tid];
            gqv[tid] = s * 0.08838834764831845f;
        }
        __syncthreads();
    }
    {
        float* lg = qkl;
        int g = tid & 7;
        for (int it = 0; it < 8; ++it) {
            int n = it * 128 + (tid >> 3);
            if (n < NN) {
                const float4* xr = (const float4*)(X + xoff + (size_t)n * DD);
                float a = 0.f;
                for (int i = 0; i < 4; ++i) {
                    float4 v = xr[g + 8 * i];
                    int col = 4 * (g + 8 * i);
                    a += v.x * gqv[col] + v.y * gqv[col + 1] + v.z * gqv[col + 2] + v.w * gqv[col + 3];
                }
                a += __shfl_xor(a, 1, 8);
                a += __shfl_xor(a, 2, 8);
                a += __shfl_xor(a, 4, 8);
                if (g == 0) {
                    float lgt = 10.0f * tanhf(a);
                    lg[n] = get_mask(mask, flag, (size_t)b * NN + n) ? NEG : lgt;
                }
            }
        }
        __syncthreads();
        float v = (tid < NN) ? lg[tid] : -INFINITY;
        float mx = v;
        for (int off = 32; off >= 1; off >>= 1) mx = fmaxf(mx, __shfl_xor(mx, off, 64));
        if ((tid & 63) == 0) red[tid >> 6] = mx;
        __syncthreads();
        float m = red[0];
        for (int w = 1; w < 16; ++w) m = fmaxf(m, red[w]);
        float e = (tid < NN) ? __expf(v - m) : 0.f;
        float sm = e;
        for (int off = 32; off >= 1; off >>= 1) sm += __shfl_xor(sm, off, 64);
        __syncthreads();
        if ((tid & 63) == 0) red[tid >> 6] = sm;
        __syncthreads();
        float s2 = 0.f;
        for (int w = 0; w < 16; ++w) s2 += red[w];
        float lse = m + logf(s2);
        if (tid < NN) out[(size_t)b * NN + tid] = v - lse;
    }
}

// ---------------------------------------------------------------------------
extern "C" void kernel_launch(void* const* d_in, const int* in_sizes, int n_in,
                              void* d_out, int out_size, void* d_ws, size_t ws_size,
                              hipStream_t stream) {
    const float* X     = (const float*)d_in[0];
    const float* Wnode = (const float*)d_in[1];
    const float* Wfix  = (const float*)d_in[2];
    const float* Wstep = (const float*)d_in[3];
    const float* Wout  = (const float*)d_in[4];
    const int*   prev  = (const int*)d_in[5];
    const int*   first = (const int*)d_in[6];
    const void*  mask  = d_in[7];
    float* out = (float*)d_out;

    char* wsb = (char*)d_ws;
    int*   syg     = (int*)wsb;                              // 256*16 ints = 16 KB
    float* partial = (float*)(wsb + 16384);                  // B*Q*D   = 131072 f
    float* sqw     = partial + (size_t)BB * QQ * DD;         // B*Q*H   = 8192 f
    float* pvp     = sqw + (size_t)BB * QQ * HH;             // B*Q*H*D = 1048576 f
    float* esumg   = pvp + (size_t)BB * QQ * HH * DD;        // B*Q     = 1024 f
    const size_t need = 16384 + sizeof(float) * (
        (size_t)BB * QQ * DD + (size_t)BB * QQ * HH +
        (size_t)BB * QQ * HH * DD + (size_t)BB * QQ);

    int maxb = 0;
    bool ok = (ws_size >= need) &&
              (hipOccupancyMaxActiveBlocksPerMultiprocessor(&maxb, (const void*)k_one,
                                                            256, 0) == hipSuccess) &&
              (maxb >= QQ);
    if (ok) {
        hipMemsetAsync(syg, 0, 16384, stream);   // counters zero on every call
        k_one<<<BB * QQ, 256, 0, stream>>>(X, Wnode, Wfix, Wstep, Wout, prev, first,
                                           mask, syg, partial, sqw, pvp, esumg, out);
    } else {
        k_mega<<<BB, 1024, 0, stream>>>(X, Wnode, Wfix, Wstep, Wout,
                                        prev, first, mask, out);
    }
}